// Round 6
// baseline (673.924 us; speedup 1.0000x reference)
//
#include <hip/hip_runtime.h>
#include <cstddef>

#define B_     512
#define IN_    1023
#define INP1   1024
#define OUT_   512
#define OUT4   128
#define CLIPV  2.0f
#define LNEPS  1e-5f

// L3 batching: 64 samples x 2 MiB = 128 MiB slice << 256 MiB Infinity Cache
#define BATCH  64
#define NBATCH 8
#define S1     16      // k1 strips per sample (64 rows each)
#define R1     64
#define S2     8       // k2 strips per sample (128 rows each)
#define R2     128

typedef float fx4 __attribute__((ext_vector_type(4)));

__device__ __forceinline__ float2 block_reduce2(float a, float b, float2* lds) {
    #pragma unroll
    for (int off = 32; off; off >>= 1) {
        a += __shfl_down(a, off, 64);
        b += __shfl_down(b, off, 64);
    }
    const int lane = threadIdx.x & 63;
    const int wid  = threadIdx.x >> 6;
    const int nw   = blockDim.x >> 6;
    if (lane == 0) lds[wid] = make_float2(a, b);
    __syncthreads();
    if (wid == 0) {
        float2 v = (lane < nw) ? lds[lane] : make_float2(0.f, 0.f);
        a = v.x; b = v.y;
        #pragma unroll
        for (int off = 8; off; off >>= 1) {
            a += __shfl_down(a, off, 64);
            b += __shfl_down(b, off, 64);
        }
        if (lane == 0) lds[0] = make_float2(a, b);
    }
    __syncthreads();
    float2 r = lds[0];
    __syncthreads();
    return r;
}

// k1a: strip partial y_pre for one batch. 1024 blocks x 256 thr (4/CU).
// Regular hebb loads on purpose: we WANT L3 allocation for k2f's re-read.
__global__ __launch_bounds__(256) void k1a_partial(
    const float* __restrict__ x, const float* __restrict__ hebb,
    const float* __restrict__ weight, const float* __restrict__ alpha,
    float* __restrict__ ws_part, int b0)
{
    const int blk  = (int)blockIdx.x;    // bl*S1 + s  (s fastest -> XCD spreads s)
    const int bl   = blk >> 4;
    const int s    = blk & (S1 - 1);
    const int b    = b0 + bl;
    const int tid  = (int)threadIdx.x;
    const int o4   = tid & 127;
    const int half = tid >> 7;           // 0..1

    __shared__ float  xs[R1];
    __shared__ float4 part[2][OUT4];

    if (tid < R1) {
        const int row = s * R1 + tid;
        xs[tid] = (row < IN_) ? x[(size_t)b * IN_ + row] : 1.0f;  // bias row = 1
    }
    __syncthreads();

    const int r0 = s * R1 + half * 32;
    const float4* __restrict__ h4 = (const float4*)hebb   + ((size_t)b * INP1 + r0) * OUT4 + o4;
    const float4* __restrict__ w4 = (const float4*)weight + (size_t)r0 * OUT4 + o4;
    const float4* __restrict__ a4 = (const float4*)alpha  + (size_t)r0 * OUT4 + o4;
    const float*  __restrict__ xk = xs + half * 32;

    float4 acc = make_float4(0.f, 0.f, 0.f, 0.f);
    #pragma unroll 8
    for (int k = 0; k < 32; ++k) {
        const float  xv = xk[k];
        const float4 h  = h4[(size_t)k * OUT4];
        const float4 w  = w4[(size_t)k * OUT4];
        const float4 a  = a4[(size_t)k * OUT4];
        acc.x = fmaf(xv, fmaf(a.x, h.x, w.x), acc.x);
        acc.y = fmaf(xv, fmaf(a.y, h.y, w.y), acc.y);
        acc.z = fmaf(xv, fmaf(a.z, h.z, w.z), acc.z);
        acc.w = fmaf(xv, fmaf(a.w, h.w, w.w), acc.w);
    }

    part[half][o4] = acc;
    __syncthreads();
    if (half == 0) {
        float4 p = part[0][o4];
        const float4 q = part[1][o4];
        p.x += q.x; p.y += q.y; p.z += q.z; p.w += q.w;
        ((float4*)ws_part)[((size_t)bl * S1 + s) * OUT4 + o4] = p;
    }
}

// k2f: per (sample, 128-row strip) block: redundant LN+modulator from the 16
// strip partials (L2-cheap), then hebb update. hebb read hits L3 (just
// streamed by k1a of the SAME batch). NT stores keep hebb_out out of caches.
// 512 blocks x 512 thr (2/CU).
__global__ __launch_bounds__(512) void k2f_ln_update(
    const float* __restrict__ x, const float* __restrict__ hebb,
    const float* __restrict__ ws_part,
    const float* __restrict__ ln_g, const float* __restrict__ ln_b,
    const float* __restrict__ mod_w, const float* __restrict__ mod_b,
    const float* __restrict__ fan_w, const float* __restrict__ fan_b,
    float* __restrict__ y_out, float* __restrict__ m_out,
    float* __restrict__ hebb_out, int b0)
{
    const int blk = (int)blockIdx.x;     // bl*S2 + s
    const int bl  = blk >> 3;
    const int s   = blk & (S2 - 1);
    const int b   = b0 + bl;
    const int tid = (int)threadIdx.x;
    const int o   = tid;                 // 0..511

    __shared__ float  xs[R2];
    __shared__ float  y_lds[OUT_];
    __shared__ float2 rbuf[16];

    // ---- LN + modulator (redundant per strip-block; reads are L2-hot) ----
    float ypre = 0.f;
    #pragma unroll
    for (int t = 0; t < S1; ++t)
        ypre += ws_part[((size_t)bl * S1 + t) * OUT_ + o];

    float2 ss = block_reduce2(ypre, ypre * ypre, rbuf);
    const float mu   = ss.x * (1.0f / OUT_);
    const float var  = ss.y * (1.0f / OUT_) - mu * mu;
    const float rstd = rsqrtf(var + LNEPS);
    const float yv   = tanhf(fmaf(ln_g[o], (ypre - mu) * rstd, ln_b[o]));
    y_lds[o] = yv;
    if (s == 0) y_out[(size_t)b * OUT_ + o] = yv;

    float2 ms = block_reduce2(yv * mod_w[o], 0.f, rbuf);
    const float mval = tanhf(ms.x + mod_b[0]);
    if (s == 0 && tid == 0) m_out[b] = mval;

    if (tid < R2) {
        const int row = s * R2 + tid;
        xs[tid] = (row < IN_) ? x[(size_t)b * IN_ + row] : 1.0f;
    }
    __syncthreads();   // y_lds + xs visible

    // ---- hebb update ----
    const int o4 = tid & 127;
    const int q  = tid >> 7;             // 0..3, 32 rows each
    const float4 yv4 = ((const float4*)y_lds)[o4];
    const float4 fw  = ((const float4*)fan_w)[o4];
    const float4 fb  = ((const float4*)fan_b)[o4];
    fx4 coef;
    coef.x = fmaf(mval, fw.x, fb.x) * yv4.x;
    coef.y = fmaf(mval, fw.y, fb.y) * yv4.y;
    coef.z = fmaf(mval, fw.z, fb.z) * yv4.z;
    coef.w = fmaf(mval, fw.w, fb.w) * yv4.w;

    const int r0 = s * R2 + q * 32;
    const size_t base = ((size_t)b * INP1 + r0) * OUT4 + o4;
    const fx4* __restrict__ h4  = (const fx4*)hebb + base;
    fx4* __restrict__       ho4 = (fx4*)hebb_out + base;
    const float* __restrict__ xk = xs + q * 32;

    #pragma unroll 8
    for (int k = 0; k < 32; ++k) {
        const float xv = xk[k];
        const fx4   h  = h4[(size_t)k * OUT4];
        fx4 r;
        r.x = fminf(fmaxf(fmaf(coef.x, xv, h.x), -CLIPV), CLIPV);
        r.y = fminf(fmaxf(fmaf(coef.y, xv, h.y), -CLIPV), CLIPV);
        r.z = fminf(fmaxf(fmaf(coef.z, xv, h.z), -CLIPV), CLIPV);
        r.w = fminf(fmaxf(fmaf(coef.w, xv, h.w), -CLIPV), CLIPV);
        __builtin_nontemporal_store(r, &ho4[(size_t)k * OUT4]);
    }
}

extern "C" void kernel_launch(void* const* d_in, const int* in_sizes, int n_in,
                              void* d_out, int out_size, void* d_ws, size_t ws_size,
                              hipStream_t stream) {
    const float* x      = (const float*)d_in[0];
    const float* hebb   = (const float*)d_in[1];
    const float* weight = (const float*)d_in[2];
    const float* alpha  = (const float*)d_in[3];
    const float* ln_g   = (const float*)d_in[4];
    const float* ln_b   = (const float*)d_in[5];
    const float* mod_w  = (const float*)d_in[6];
    const float* mod_b  = (const float*)d_in[7];
    const float* fan_w  = (const float*)d_in[8];
    const float* fan_b  = (const float*)d_in[9];

    float* out      = (float*)d_out;
    float* y_out    = out;                               // [B, OUT]
    float* m_out    = out + (size_t)B_ * OUT_;           // [B]
    float* hebb_out = m_out + B_;                        // [B, IN+1, OUT]

    // scratch: BATCH*S1*OUT floats = 2 MiB (R5 proved ws_size >= 16 MiB)
    float* ws_part = (float*)d_ws;

    for (int batch = 0; batch < NBATCH; ++batch) {
        const int b0 = batch * BATCH;
        k1a_partial<<<BATCH * S1, 256, 0, stream>>>(x, hebb, weight, alpha,
                                                    ws_part, b0);
        k2f_ln_update<<<BATCH * S2, 512, 0, stream>>>(x, hebb, ws_part,
                                                      ln_g, ln_b, mod_w, mod_b,
                                                      fan_w, fan_b,
                                                      y_out, m_out, hebb_out, b0);
    }
}